// Round 7
// baseline (286.086 us; speedup 1.0000x reference)
//
#include <hip/hip_runtime.h>
#include <math.h>

#define N_NODES 100000
#define N_EDGES 1600000
#define IN_DIM  128
#define C1      64        // HEADS*HID layer-1 output channels
#define OUT_DIM 32
#define NEG_SLOPE 0.2f

#define BSHIFT  8
#define BNODES  256                         // nodes per bucket
#define NBUCK   ((N_NODES + BNODES - 1) / BNODES)   // 391
#define CAP     5120                        // bucket capacity (mean 4096, +16 sigma)
#define SLOTS   48                          // per-node capacity (max degree ~35)
#define GC_STRIDE 16                        // bucket cursor: one per 64B line
#define NB_GEMM ((N_NODES + 255) / 256)     // 391
#define G1_ROWS 512                         // rows per gemm1 block (256 thr x M=2)
#define NB_G1   ((N_NODES + G1_ROWS - 1) / G1_ROWS)  // 196

typedef _Float16 half8 __attribute__((ext_vector_type(8)));

__device__ __forceinline__ void fma4(float4& a, float s, const float4 b) {
    a.x = fmaf(s, b.x, a.x);
    a.y = fmaf(s, b.y, a.y);
    a.z = fmaf(s, b.z, a.z);
    a.w = fmaf(s, b.w, a.w);
}
__device__ __forceinline__ float dot4(const float4 a, const float4 b) {
    return a.x*b.x + a.y*b.y + a.z*b.z + a.w*b.w;
}
__device__ __forceinline__ float lrelu_exp(float sc) {
    sc = sc >= 0.f ? sc : NEG_SLOPE * sc;
    return __expf(sc);
}

// ---------------- binned CSR build ----------------

__global__ void zero_k(int4* __restrict__ p, int n4) {
    int i = blockIdx.x * 256 + threadIdx.x;
    if (i < n4) p[i] = make_int4(0, 0, 0, 0);
}

// P1: bin edges by dst>>8. Per-block LDS histogram -> one global atomic per
// bucket per block -> packed (src | local_dst<<17) into contiguous bucket runs.
__global__ __launch_bounds__(1024) void binp1_k(const int* __restrict__ ei,
        int* __restrict__ gcur, int* __restrict__ buf) {
    __shared__ int scnt[NBUCK], sbase[NBUCK], soff[NBUCK];
    int t = threadIdx.x;
    if (t < NBUCK) { scnt[t] = 0; soff[t] = 0; }
    __syncthreads();
    int  s[16], bk[16], ld[16];
    bool v[16];
    #pragma unroll
    for (int i = 0; i < 16; ++i) {
        int e = blockIdx.x * 16384 + i * 1024 + t;
        v[i] = e < N_EDGES;
        int ec = v[i] ? e : 0;
        s[i] = ei[ec];
        int d = ei[N_EDGES + ec];
        bk[i] = d >> BSHIFT;
        ld[i] = d & (BNODES - 1);
        if (v[i]) atomicAdd(&scnt[bk[i]], 1);
    }
    __syncthreads();
    if (t < NBUCK) sbase[t] = atomicAdd(&gcur[t * GC_STRIDE], scnt[t]);
    __syncthreads();
    #pragma unroll
    for (int i = 0; i < 16; ++i) {
        if (v[i]) {
            int p = sbase[bk[i]] + atomicAdd(&soff[bk[i]], 1);
            if (p < CAP) buf[bk[i] * CAP + p] = s[i] | (ld[i] << 17);
        }
    }
}

// P2: one block per bucket. Place the bucket's edges into 256-node x 48-slot
// LDS rows via LDS atomics, then stream out as coalesced int4 + dense deg[].
__global__ __launch_bounds__(256) void binp2_k(const int* __restrict__ gcur,
        const int* __restrict__ buf, int* __restrict__ csr, int* __restrict__ deg) {
    __shared__ int4 lcsr4[BNODES * SLOTS / 4];   // 48 KiB
    __shared__ int  lcnt[BNODES];
    int* lcsr = (int*)lcsr4;
    int b = blockIdx.x, t = threadIdx.x;
    lcnt[t] = 0;
    __syncthreads();
    int cnt = gcur[b * GC_STRIDE];
    if (cnt > CAP) cnt = CAP;
    const int* bb = buf + b * CAP;
    for (int e = t; e < cnt; e += 256) {
        int vv = bb[e];
        int src = vv & 0x1FFFF;
        int l = vv >> 17;
        int slot = atomicAdd(&lcnt[l], 1);
        if (slot < SLOTS) lcsr[l * SLOTS + slot] = src;
    }
    __syncthreads();
    int4* g4 = (int4*)csr + (size_t)b * (BNODES * SLOTS / 4);
    #pragma unroll
    for (int i = 0; i < BNODES * SLOTS / 4 / 256; ++i)   // 12 int4/thread
        g4[t + i * 256] = lcsr4[t + i * 256];
    int c = lcnt[t];
    deg[b * BNODES + t] = c < SLOTS ? c : SLOTS;
}

// ---------------- GEMM + fused attention-score dots ----------------
// Layer 1: h1[N][64] (fp16) = x[N][128] @ W1[128][64].
// M=2 rows/thread, N-split by head (blockIdx.y): each block computes 512 rows
// x 32 channels. Each LDS W read feeds 8 FMAs (2 rows x float4) -> VALU-bound.
// Attention dots split cleanly: head h's score uses only channels h*32..h*32+31.
__global__ __launch_bounds__(256) void gemm1_k(const float* __restrict__ x,
        const float* __restrict__ W, const float* __restrict__ a_s,
        const float* __restrict__ a_d, _Float16* __restrict__ h,
        float* __restrict__ as_o, float* __restrict__ ad_o) {
    __shared__ float4 Wl[IN_DIM * 8];        // 128 k x 8 float4 (32 ch) = 16 KiB
    int t = threadIdx.x;
    int head = blockIdx.y;
    const float4* Wg = (const float4*)W;     // [128][16] float4
    #pragma unroll
    for (int j = 0; j < 4; ++j) {            // 1024 float4 total
        int i = t + 256 * j;
        int k = i >> 3, c4 = i & 7;
        Wl[i] = Wg[k * 16 + head * 8 + c4];
    }
    __syncthreads();
    int r0 = blockIdx.x * G1_ROWS + t;
    int r1 = r0 + 256;
    bool v0 = r0 < N_NODES, v1 = r1 < N_NODES;
    float4 acc0[8], acc1[8];
    #pragma unroll
    for (int i = 0; i < 8; ++i) {
        acc0[i] = make_float4(0.f, 0.f, 0.f, 0.f);
        acc1[i] = make_float4(0.f, 0.f, 0.f, 0.f);
    }
    const float4* xr0 = (const float4*)(x + (size_t)(v0 ? r0 : 0) * IN_DIM);
    const float4* xr1 = (const float4*)(x + (size_t)(v1 ? r1 : 0) * IN_DIM);
    #pragma unroll 2
    for (int k4 = 0; k4 < IN_DIM / 4; ++k4) {
        float4 xv0 = xr0[k4];
        float4 xv1 = xr1[k4];
        const float4* w0 = &Wl[(4 * k4 + 0) * 8];
        const float4* w1 = &Wl[(4 * k4 + 1) * 8];
        const float4* w2 = &Wl[(4 * k4 + 2) * 8];
        const float4* w3 = &Wl[(4 * k4 + 3) * 8];
        #pragma unroll
        for (int c = 0; c < 8; ++c) {
            float4 a = w0[c], b = w1[c], cc = w2[c], dd = w3[c];
            fma4(acc0[c], xv0.x, a);  fma4(acc1[c], xv1.x, a);
            fma4(acc0[c], xv0.y, b);  fma4(acc1[c], xv1.y, b);
            fma4(acc0[c], xv0.z, cc); fma4(acc1[c], xv1.z, cc);
            fma4(acc0[c], xv0.w, dd); fma4(acc1[c], xv1.w, dd);
        }
    }
    const float4* As = (const float4*)(a_s + head * 32);
    const float4* Ad = (const float4*)(a_d + head * 32);
    float s0 = 0.f, d0 = 0.f, s1 = 0.f, d1 = 0.f;
    #pragma unroll
    for (int c = 0; c < 8; ++c) {
        s0 += dot4(acc0[c], As[c]); d0 += dot4(acc0[c], Ad[c]);
        s1 += dot4(acc1[c], As[c]); d1 += dot4(acc1[c], Ad[c]);
    }
    if (v0) {
        as_o[r0 * 2 + head] = s0; ad_o[r0 * 2 + head] = d0;
        _Float16* hr = h + (size_t)r0 * C1 + head * 32;
        #pragma unroll
        for (int j = 0; j < 4; ++j) {
            float4 a = acc0[2 * j], b = acc0[2 * j + 1];
            half8 hv;
            hv[0] = (_Float16)a.x; hv[1] = (_Float16)a.y;
            hv[2] = (_Float16)a.z; hv[3] = (_Float16)a.w;
            hv[4] = (_Float16)b.x; hv[5] = (_Float16)b.y;
            hv[6] = (_Float16)b.z; hv[7] = (_Float16)b.w;
            *(half8*)(hr + 8 * j) = hv;
        }
    }
    if (v1) {
        as_o[r1 * 2 + head] = s1; ad_o[r1 * 2 + head] = d1;
        _Float16* hr = h + (size_t)r1 * C1 + head * 32;
        #pragma unroll
        for (int j = 0; j < 4; ++j) {
            float4 a = acc1[2 * j], b = acc1[2 * j + 1];
            half8 hv;
            hv[0] = (_Float16)a.x; hv[1] = (_Float16)a.y;
            hv[2] = (_Float16)a.z; hv[3] = (_Float16)a.w;
            hv[4] = (_Float16)b.x; hv[5] = (_Float16)b.y;
            hv[6] = (_Float16)b.z; hv[7] = (_Float16)b.w;
            *(half8*)(hr + 8 * j) = hv;
        }
    }
}

// Layer 2: h2[N][32] (fp16) = helu[N][64] @ W2[64][32]; 1 head.
__global__ __launch_bounds__(256) void gemm2_k(const float* __restrict__ x,
        const float* __restrict__ W, const float* __restrict__ a_s,
        const float* __restrict__ a_d, _Float16* __restrict__ h,
        float* __restrict__ as_o, float* __restrict__ ad_o) {
    __shared__ float4 Wl[C1 * OUT_DIM / 4];  // 512 float4 = 8 KiB
    int t = threadIdx.x;
    const float4* Wg = (const float4*)W;
    #pragma unroll
    for (int i = 0; i < 2; ++i) Wl[t + 256 * i] = Wg[t + 256 * i];
    __syncthreads();
    int row = blockIdx.x * 256 + t;
    if (row >= N_NODES) return;
    float4 acc[8];
    #pragma unroll
    for (int i = 0; i < 8; ++i) acc[i] = make_float4(0.f, 0.f, 0.f, 0.f);
    const float4* xr = (const float4*)(x + (size_t)row * C1);
    #pragma unroll 2
    for (int k4 = 0; k4 < C1 / 4; ++k4) {
        float4 xv = xr[k4];
        const float4* w0 = &Wl[(4 * k4 + 0) * (OUT_DIM / 4)];
        const float4* w1 = &Wl[(4 * k4 + 1) * (OUT_DIM / 4)];
        const float4* w2 = &Wl[(4 * k4 + 2) * (OUT_DIM / 4)];
        const float4* w3 = &Wl[(4 * k4 + 3) * (OUT_DIM / 4)];
        #pragma unroll
        for (int c = 0; c < 8; ++c) {
            fma4(acc[c], xv.x, w0[c]);
            fma4(acc[c], xv.y, w1[c]);
            fma4(acc[c], xv.z, w2[c]);
            fma4(acc[c], xv.w, w3[c]);
        }
    }
    const float4* As = (const float4*)a_s;   // [32] flat
    const float4* Ad = (const float4*)a_d;
    float s0 = 0.f, d0 = 0.f;
    #pragma unroll
    for (int c = 0; c < 8; ++c) {
        s0 += dot4(acc[c], As[c]);
        d0 += dot4(acc[c], Ad[c]);
    }
    as_o[row] = s0; ad_o[row] = d0;
    _Float16* hr = h + (size_t)row * OUT_DIM;
    #pragma unroll
    for (int j = 0; j < 4; ++j) {
        float4 a0 = acc[2 * j], a1 = acc[2 * j + 1];
        half8 hv;
        hv[0] = (_Float16)a0.x; hv[1] = (_Float16)a0.y;
        hv[2] = (_Float16)a0.z; hv[3] = (_Float16)a0.w;
        hv[4] = (_Float16)a1.x; hv[5] = (_Float16)a1.y;
        hv[6] = (_Float16)a1.z; hv[7] = (_Float16)a1.w;
        *(half8*)(hr + 8 * j) = hv;
    }
}

// ---------------- Aggregation (segment softmax + weighted sum, gather-only) ----

// Layer 1: one wave per dst node. 8 lanes per edge x 8 edge groups:
// eg = lane>>3 picks the edge, cl = lane&7 picks 8 halfs (16B) of the 128B row.
// fp32 accumulation via float(h16)*w+acc (compiles to v_fma_mix_f32).
// 16 gathers in flight per iteration; 3-round shfl_xor butterfly at the end.
__global__ __launch_bounds__(256) void agg1_k(const int* __restrict__ deg,
        const int* __restrict__ csr, const _Float16* __restrict__ h1,
        const float* __restrict__ as1, const float* __restrict__ ad1,
        const float* __restrict__ b1, float* __restrict__ helu) {
    int d = (blockIdx.x * 256 + threadIdx.x) >> 6;
    int lane = threadIdx.x & 63;
    int eg = lane >> 3;          // edge group 0..7
    int cl = lane & 7;           // 8-half channel group
    int head = cl >> 2;          // cl 0-3 -> head 0 (ch 0-31), 4-7 -> head 1
    int cnt = deg[d];
    const int* row = csr + d * SLOTS;
    float advl = ad1[d * 2 + head];
    float acc[8] = {0.f, 0.f, 0.f, 0.f, 0.f, 0.f, 0.f, 0.f};
    float wsum = 0.f;
    for (int base = 0; base < cnt; base += 16) {
        int e0 = base + eg, e1 = base + 8 + eg;
        bool v0 = e0 < cnt, v1 = e1 < cnt;
        int s0 = row[v0 ? e0 : 0];
        int s1 = row[v1 ? e1 : 0];
        float a0 = as1[s0 * 2 + head];
        float a1 = as1[s1 * 2 + head];
        half8 g0 = *(const half8*)(h1 + (size_t)s0 * C1 + 8 * cl);
        half8 g1 = *(const half8*)(h1 + (size_t)s1 * C1 + 8 * cl);
        float w0 = lrelu_exp(a0 + advl) * (v0 ? 1.f : 0.f);
        float w1 = lrelu_exp(a1 + advl) * (v1 ? 1.f : 0.f);
        #pragma unroll
        for (int i = 0; i < 8; ++i) {
            acc[i] = fmaf((float)g0[i], w0, acc[i]);
            acc[i] = fmaf((float)g1[i], w1, acc[i]);
        }
        wsum += w0 + w1;
    }
    if (eg == 0) {   // self loop (src = dst)
        float w = lrelu_exp(as1[d * 2 + head] + advl);
        half8 g = *(const half8*)(h1 + (size_t)d * C1 + 8 * cl);
        #pragma unroll
        for (int i = 0; i < 8; ++i) acc[i] = fmaf((float)g[i], w, acc[i]);
        wsum += w;
    }
    #pragma unroll
    for (int m = 8; m <= 32; m <<= 1) {   // butterfly over eg axis
        #pragma unroll
        for (int i = 0; i < 8; ++i) acc[i] += __shfl_xor(acc[i], m);
        wsum += __shfl_xor(wsum, m);
    }
    if (eg == 0) {
        float inv = 1.f / (wsum + 1e-16f);
        const float4* bv = (const float4*)(b1 + 8 * cl);
        float4 o0, o1;
        o0.x = acc[0] * inv + bv[0].x; o0.y = acc[1] * inv + bv[0].y;
        o0.z = acc[2] * inv + bv[0].z; o0.w = acc[3] * inv + bv[0].w;
        o1.x = acc[4] * inv + bv[1].x; o1.y = acc[5] * inv + bv[1].y;
        o1.z = acc[6] * inv + bv[1].z; o1.w = acc[7] * inv + bv[1].w;
        o0.x = o0.x > 0.f ? o0.x : __expf(o0.x) - 1.f;
        o0.y = o0.y > 0.f ? o0.y : __expf(o0.y) - 1.f;
        o0.z = o0.z > 0.f ? o0.z : __expf(o0.z) - 1.f;
        o0.w = o0.w > 0.f ? o0.w : __expf(o0.w) - 1.f;
        o1.x = o1.x > 0.f ? o1.x : __expf(o1.x) - 1.f;
        o1.y = o1.y > 0.f ? o1.y : __expf(o1.y) - 1.f;
        o1.z = o1.z > 0.f ? o1.z : __expf(o1.z) - 1.f;
        o1.w = o1.w > 0.f ? o1.w : __expf(o1.w) - 1.f;
        float4* hw = (float4*)(helu + (size_t)d * C1 + 8 * cl);
        hw[0] = o0;
        hw[1] = o1;
    }
}

// Layer 2: 4 lanes per edge x 16 edge groups; cl = lane&3 spans the 64B row.
// Butterfly over xor 4/8/16/32. Mean over 1 head = identity; +b2.
__global__ __launch_bounds__(256) void agg2_k(const int* __restrict__ deg,
        const int* __restrict__ csr, const _Float16* __restrict__ h2,
        const float* __restrict__ as2, const float* __restrict__ ad2,
        const float* __restrict__ b2, float* __restrict__ out) {
    int d = (blockIdx.x * 256 + threadIdx.x) >> 6;
    int lane = threadIdx.x & 63;
    int eg = lane >> 2;          // edge group 0..15
    int cl = lane & 3;           // 8-half channel group
    int cnt = deg[d];
    const int* row = csr + d * SLOTS;
    float advl = ad2[d];
    float acc[8] = {0.f, 0.f, 0.f, 0.f, 0.f, 0.f, 0.f, 0.f};
    float wsum = 0.f;
    for (int base = 0; base < cnt; base += 32) {
        int e0 = base + eg, e1 = base + 16 + eg;
        bool v0 = e0 < cnt, v1 = e1 < cnt;
        int s0 = row[v0 ? e0 : 0];
        int s1 = row[v1 ? e1 : 0];
        float a0 = as2[s0];
        float a1 = as2[s1];
        half8 g0 = *(const half8*)(h2 + (size_t)s0 * OUT_DIM + 8 * cl);
        half8 g1 = *(const half8*)(h2 + (size_t)s1 * OUT_DIM + 8 * cl);
        float w0 = lrelu_exp(a0 + advl) * (v0 ? 1.f : 0.f);
        float w1 = lrelu_exp(a1 + advl) * (v1 ? 1.f : 0.f);
        #pragma unroll
        for (int i = 0; i < 8; ++i) {
            acc[i] = fmaf((float)g0[i], w0, acc[i]);
            acc[i] = fmaf((float)g1[i], w1, acc[i]);
        }
        wsum += w0 + w1;
    }
    if (eg == 0) {   // self loop
        float w = lrelu_exp(as2[d] + advl);
        half8 g = *(const half8*)(h2 + (size_t)d * OUT_DIM + 8 * cl);
        #pragma unroll
        for (int i = 0; i < 8; ++i) acc[i] = fmaf((float)g[i], w, acc[i]);
        wsum += w;
    }
    #pragma unroll
    for (int m = 4; m <= 32; m <<= 1) {    // butterfly over eg axis
        #pragma unroll
        for (int i = 0; i < 8; ++i) acc[i] += __shfl_xor(acc[i], m);
        wsum += __shfl_xor(wsum, m);
    }
    if (eg == 0) {
        float inv = 1.f / (wsum + 1e-16f);
        const float4* bv = (const float4*)(b2 + 8 * cl);
        float4 o0, o1;
        o0.x = acc[0] * inv + bv[0].x; o0.y = acc[1] * inv + bv[0].y;
        o0.z = acc[2] * inv + bv[0].z; o0.w = acc[3] * inv + bv[0].w;
        o1.x = acc[4] * inv + bv[1].x; o1.y = acc[5] * inv + bv[1].y;
        o1.z = acc[6] * inv + bv[1].z; o1.w = acc[7] * inv + bv[1].w;
        float4* ow = (float4*)(out + (size_t)d * OUT_DIM + 8 * cl);
        ow[0] = o0;
        ow[1] = o1;
    }
}

// ---------------- launch ----------------

extern "C" void kernel_launch(void* const* d_in, const int* in_sizes, int n_in,
                              void* d_out, int out_size, void* d_ws, size_t ws_size,
                              hipStream_t stream) {
    const float* x   = (const float*)d_in[0];
    const int*   ei  = (const int*)d_in[1];
    const float* W1  = (const float*)d_in[2];
    const float* a1s = (const float*)d_in[3];
    const float* a1d = (const float*)d_in[4];
    const float* b1  = (const float*)d_in[5];
    const float* W2  = (const float*)d_in[6];
    const float* a2s = (const float*)d_in[7];
    const float* a2d = (const float*)d_in[8];
    const float* b2  = (const float*)d_in[9];
    float* out = (float*)d_out;

    char* ws = (char*)d_ws;
    size_t off = 0;
    auto alloc = [&](size_t bytes) -> void* {
        void* p = ws + off;
        off = (off + bytes + 255) & ~(size_t)255;
        return p;
    };
    int* gcur      = (int*)alloc((size_t)NBUCK * GC_STRIDE * 4);        // 25 KB
    int* buf       = (int*)alloc((size_t)NBUCK * CAP * 4);              // 8 MB
    int* csr       = (int*)alloc((size_t)NBUCK * BNODES * SLOTS * 4);   // 19.2 MB
    int* deg       = (int*)alloc((size_t)NBUCK * BNODES * 4);           // 0.4 MB
    _Float16* h1   = (_Float16*)alloc((size_t)N_NODES * C1 * 2);        // 12.8 MB
    float* as1     = (float*)alloc((size_t)N_NODES * 2 * 4);
    float* ad1     = (float*)alloc((size_t)N_NODES * 2 * 4);
    float* helu    = (float*)alloc((size_t)N_NODES * C1 * 4);
    _Float16* h2   = (_Float16*)alloc((size_t)N_NODES * OUT_DIM * 2);   // 6.4 MB
    float* as2     = (float*)alloc((size_t)N_NODES * 4);
    float* ad2     = (float*)alloc((size_t)N_NODES * 4);

    const int ZN4 = NBUCK * GC_STRIDE / 4;
    zero_k<<<(ZN4 + 255) / 256, 256, 0, stream>>>((int4*)gcur, ZN4);
    binp1_k<<<(N_EDGES + 16383) / 16384, 1024, 0, stream>>>(ei, gcur, buf);
    binp2_k<<<NBUCK, 256, 0, stream>>>(gcur, buf, csr, deg);

    gemm1_k<<<dim3(NB_G1, 2), 256, 0, stream>>>(x, W1, a1s, a1d, h1, as1, ad1);
    agg1_k<<<N_NODES / 4, 256, 0, stream>>>(deg, csr, h1, as1, ad1, b1, helu);
    gemm2_k<<<NB_GEMM, 256, 0, stream>>>(helu, W2, a2s, a2d, h2, as2, ad2);
    agg2_k<<<N_NODES / 4, 256, 0, stream>>>(deg, csr, h2, as2, ad2, b2, out);
}

// Round 8
// 253.342 us; speedup vs baseline: 1.1292x; 1.1292x over previous
//
#include <hip/hip_runtime.h>
#include <math.h>

#define N_NODES 100000
#define N_EDGES 1600000
#define IN_DIM  128
#define C1      64        // HEADS*HID layer-1 output channels
#define OUT_DIM 32
#define NEG_SLOPE 0.2f

#define BSHIFT  8
#define BNODES  256                         // nodes per bucket
#define NBUCK   ((N_NODES + BNODES - 1) / BNODES)   // 391
#define CAP     5120                        // bucket capacity (mean 4096, +16 sigma)
#define SLOTS   48                          // per-node capacity (max degree ~35)
#define GC_STRIDE 16                        // bucket cursor: one per 64B line
#define G1_BLOCKS ((N_NODES + 127) / 128)   // 782 (128 rows/block, 32/wave)

typedef _Float16 half8 __attribute__((ext_vector_type(8)));
typedef float    f32x4 __attribute__((ext_vector_type(4)));

__device__ __forceinline__ float lrelu_exp(float sc) {
    sc = sc >= 0.f ? sc : NEG_SLOPE * sc;
    return __expf(sc);
}

// ---------------- binned CSR build ----------------

__global__ void zero_k(int4* __restrict__ p, int n4) {
    int i = blockIdx.x * 256 + threadIdx.x;
    if (i < n4) p[i] = make_int4(0, 0, 0, 0);
}

// P1: bin edges by dst>>8. Per-block LDS histogram -> one global atomic per
// bucket per block -> packed (src | local_dst<<17) into contiguous bucket runs.
__global__ __launch_bounds__(1024) void binp1_k(const int* __restrict__ ei,
        int* __restrict__ gcur, int* __restrict__ buf) {
    __shared__ int scnt[NBUCK], sbase[NBUCK], soff[NBUCK];
    int t = threadIdx.x;
    if (t < NBUCK) { scnt[t] = 0; soff[t] = 0; }
    __syncthreads();
    int  s[16], bk[16], ld[16];
    bool v[16];
    #pragma unroll
    for (int i = 0; i < 16; ++i) {
        int e = blockIdx.x * 16384 + i * 1024 + t;
        v[i] = e < N_EDGES;
        int ec = v[i] ? e : 0;
        s[i] = ei[ec];
        int d = ei[N_EDGES + ec];
        bk[i] = d >> BSHIFT;
        ld[i] = d & (BNODES - 1);
        if (v[i]) atomicAdd(&scnt[bk[i]], 1);
    }
    __syncthreads();
    if (t < NBUCK) sbase[t] = atomicAdd(&gcur[t * GC_STRIDE], scnt[t]);
    __syncthreads();
    #pragma unroll
    for (int i = 0; i < 16; ++i) {
        if (v[i]) {
            int p = sbase[bk[i]] + atomicAdd(&soff[bk[i]], 1);
            if (p < CAP) buf[bk[i] * CAP + p] = s[i] | (ld[i] << 17);
        }
    }
}

// P2: one block per bucket. Place the bucket's edges into 256-node x 48-slot
// LDS rows via LDS atomics, then stream out as coalesced int4 + dense deg[].
__global__ __launch_bounds__(256) void binp2_k(const int* __restrict__ gcur,
        const int* __restrict__ buf, int* __restrict__ csr, int* __restrict__ deg) {
    __shared__ int4 lcsr4[BNODES * SLOTS / 4];   // 48 KiB
    __shared__ int  lcnt[BNODES];
    int* lcsr = (int*)lcsr4;
    int b = blockIdx.x, t = threadIdx.x;
    lcnt[t] = 0;
    __syncthreads();
    int cnt = gcur[b * GC_STRIDE];
    if (cnt > CAP) cnt = CAP;
    const int* bb = buf + b * CAP;
    for (int e = t; e < cnt; e += 256) {
        int vv = bb[e];
        int src = vv & 0x1FFFF;
        int l = vv >> 17;
        int slot = atomicAdd(&lcnt[l], 1);
        if (slot < SLOTS) lcsr[l * SLOTS + slot] = src;
    }
    __syncthreads();
    int4* g4 = (int4*)csr + (size_t)b * (BNODES * SLOTS / 4);
    #pragma unroll
    for (int i = 0; i < BNODES * SLOTS / 4 / 256; ++i)   // 12 int4/thread
        g4[t + i * 256] = lcsr4[t + i * 256];
    int c = lcnt[t];
    deg[b * BNODES + t] = c < SLOTS ? c : SLOTS;
}

// ---------------- weight prep: fp16 transpose for MFMA B-operand ----------------
// w1t[n][k]: n in [0,64), k in [0,128).  w2t[n][k]: n in [0,32), k in [0,64).
__global__ void prep_k(const float* __restrict__ W1, const float* __restrict__ W2,
                       _Float16* __restrict__ w1t, _Float16* __restrict__ w2t) {
    int t = blockIdx.x * 256 + threadIdx.x;
    if (t < IN_DIM * C1) {
        int k = t >> 6, n = t & 63;
        w1t[n * IN_DIM + k] = (_Float16)W1[t];
    }
    if (t < C1 * OUT_DIM) {
        int k = t >> 5, n = t & 31;
        w2t[n * C1 + k] = (_Float16)W2[t];
    }
}

// ---------------- MFMA GEMMs + fused attention-score dots ----------------
// gemm1: h1[N][64] fp16 = x[N][128] @ W1.  Block = 4 waves x 32 rows = 128 rows.
// Wave: 2 row-tiles x 4 ch-tiles of 16x16x32 f16 MFMA, K = 4 steps.
// A frags loaded direct from global fp32 + cvt (A[m=lane&15][k=quad*8+j]);
// B frags from w1t (B[n=lane&15][k=quad*8+j], contiguous 16B).
// Epilogue: C frags (col=lane&15,row=quad*4+reg) -> per-wave LDS slab fp16 ->
// row-major readback; lane parity=head computes full 32-ch as/ad dots.
__global__ __launch_bounds__(256) void gemm1_k(const float* __restrict__ x,
        const _Float16* __restrict__ w1t, const float* __restrict__ a_s,
        const float* __restrict__ a_d, _Float16* __restrict__ h,
        float* __restrict__ as_o, float* __restrict__ ad_o) {
    __shared__ _Float16 sh[4][32 * 72];   // 4 waves x 32 rows x (64+8 pad) = 18 KiB
    int t = threadIdx.x;
    int wv = t >> 6, lane = t & 63, m = lane & 15, q = lane >> 4;
    int rbw = blockIdx.x * 128 + wv * 32;
    f32x4 acc[2][4];
    #pragma unroll
    for (int i = 0; i < 2; ++i)
        #pragma unroll
        for (int j = 0; j < 4; ++j) acc[i][j] = (f32x4){0.f, 0.f, 0.f, 0.f};
    #pragma unroll
    for (int ks = 0; ks < 4; ++ks) {
        half8 a[2];
        #pragma unroll
        for (int rt = 0; rt < 2; ++rt) {
            int r = rbw + rt * 16 + m;
            r = r < N_NODES ? r : 0;
            const float4* p = (const float4*)(x + (size_t)r * IN_DIM + ks * 32 + q * 8);
            float4 f0 = p[0], f1 = p[1];
            half8 av;
            av[0] = (_Float16)f0.x; av[1] = (_Float16)f0.y;
            av[2] = (_Float16)f0.z; av[3] = (_Float16)f0.w;
            av[4] = (_Float16)f1.x; av[5] = (_Float16)f1.y;
            av[6] = (_Float16)f1.z; av[7] = (_Float16)f1.w;
            a[rt] = av;
        }
        #pragma unroll
        for (int ct = 0; ct < 4; ++ct) {
            half8 b = *(const half8*)(w1t + (ct * 16 + m) * IN_DIM + ks * 32 + q * 8);
            acc[0][ct] = __builtin_amdgcn_mfma_f32_16x16x32_f16(a[0], b, acc[0][ct], 0, 0, 0);
            acc[1][ct] = __builtin_amdgcn_mfma_f32_16x16x32_f16(a[1], b, acc[1][ct], 0, 0, 0);
        }
    }
    _Float16* ws = sh[wv];
    #pragma unroll
    for (int rt = 0; rt < 2; ++rt)
        #pragma unroll
        for (int ct = 0; ct < 4; ++ct)
            #pragma unroll
            for (int r = 0; r < 4; ++r)
                ws[(rt * 16 + q * 4 + r) * 72 + ct * 16 + m] = (_Float16)acc[rt][ct][r];
    __syncthreads();
    int rl = lane >> 1, hp = lane & 1;    // row-local 0..31, head = parity
    int rg = rbw + rl;
    if (rg < N_NODES) {
        float As_r[32], Ad_r[32];
        const float4* ap = (const float4*)(a_s + hp * 32);
        const float4* dp = (const float4*)(a_d + hp * 32);
        #pragma unroll
        for (int i = 0; i < 8; ++i) {
            float4 v = ap[i];
            As_r[4*i] = v.x; As_r[4*i+1] = v.y; As_r[4*i+2] = v.z; As_r[4*i+3] = v.w;
            float4 u = dp[i];
            Ad_r[4*i] = u.x; Ad_r[4*i+1] = u.y; Ad_r[4*i+2] = u.z; Ad_r[4*i+3] = u.w;
        }
        const _Float16* rowp = ws + rl * 72 + hp * 32;
        half8 c0 = *(const half8*)(rowp);
        half8 c1 = *(const half8*)(rowp + 8);
        half8 c2 = *(const half8*)(rowp + 16);
        half8 c3 = *(const half8*)(rowp + 24);
        float s = 0.f, dd = 0.f;
        #pragma unroll
        for (int j = 0; j < 8; ++j) {
            s  = fmaf((float)c0[j], As_r[j],      s);
            dd = fmaf((float)c0[j], Ad_r[j],      dd);
            s  = fmaf((float)c1[j], As_r[8 + j],  s);
            dd = fmaf((float)c1[j], Ad_r[8 + j],  dd);
            s  = fmaf((float)c2[j], As_r[16 + j], s);
            dd = fmaf((float)c2[j], Ad_r[16 + j], dd);
            s  = fmaf((float)c3[j], As_r[24 + j], s);
            dd = fmaf((float)c3[j], Ad_r[24 + j], dd);
        }
        as_o[rg * 2 + hp] = s;
        ad_o[rg * 2 + hp] = dd;
        _Float16* hr = h + (size_t)rg * C1 + hp * 32;
        *(half8*)(hr)      = c0;
        *(half8*)(hr + 8)  = c1;
        *(half8*)(hr + 16) = c2;
        *(half8*)(hr + 24) = c3;
    }
}

// gemm2: h2[N][32] fp16 = helu[N][64] fp16 @ W2.  Same structure, K=2 steps,
// 2 row-tiles x 2 ch-tiles per wave; A loads direct fp16 (no cvt).
__global__ __launch_bounds__(256) void gemm2_k(const _Float16* __restrict__ xh,
        const _Float16* __restrict__ w2t, const float* __restrict__ a_s,
        const float* __restrict__ a_d, _Float16* __restrict__ h,
        float* __restrict__ as_o, float* __restrict__ ad_o) {
    __shared__ _Float16 sh[4][32 * 36];   // 9 KiB
    int t = threadIdx.x;
    int wv = t >> 6, lane = t & 63, m = lane & 15, q = lane >> 4;
    int rbw = blockIdx.x * 128 + wv * 32;
    f32x4 acc[2][2];
    #pragma unroll
    for (int i = 0; i < 2; ++i)
        #pragma unroll
        for (int j = 0; j < 2; ++j) acc[i][j] = (f32x4){0.f, 0.f, 0.f, 0.f};
    #pragma unroll
    for (int ks = 0; ks < 2; ++ks) {
        half8 a[2];
        #pragma unroll
        for (int rt = 0; rt < 2; ++rt) {
            int r = rbw + rt * 16 + m;
            r = r < N_NODES ? r : 0;
            a[rt] = *(const half8*)(xh + (size_t)r * C1 + ks * 32 + q * 8);
        }
        #pragma unroll
        for (int ct = 0; ct < 2; ++ct) {
            half8 b = *(const half8*)(w2t + (ct * 16 + m) * C1 + ks * 32 + q * 8);
            acc[0][ct] = __builtin_amdgcn_mfma_f32_16x16x32_f16(a[0], b, acc[0][ct], 0, 0, 0);
            acc[1][ct] = __builtin_amdgcn_mfma_f32_16x16x32_f16(a[1], b, acc[1][ct], 0, 0, 0);
        }
    }
    _Float16* ws = sh[wv];
    #pragma unroll
    for (int rt = 0; rt < 2; ++rt)
        #pragma unroll
        for (int ct = 0; ct < 2; ++ct)
            #pragma unroll
            for (int r = 0; r < 4; ++r)
                ws[(rt * 16 + q * 4 + r) * 36 + ct * 16 + m] = (_Float16)acc[rt][ct][r];
    __syncthreads();
    if (lane < 32) {
        int rg = rbw + lane;
        if (rg < N_NODES) {
            float As_r[32], Ad_r[32];
            const float4* ap = (const float4*)a_s;
            const float4* dp = (const float4*)a_d;
            #pragma unroll
            for (int i = 0; i < 8; ++i) {
                float4 v = ap[i];
                As_r[4*i] = v.x; As_r[4*i+1] = v.y; As_r[4*i+2] = v.z; As_r[4*i+3] = v.w;
                float4 u = dp[i];
                Ad_r[4*i] = u.x; Ad_r[4*i+1] = u.y; Ad_r[4*i+2] = u.z; Ad_r[4*i+3] = u.w;
            }
            const _Float16* rowp = ws + lane * 36;
            half8 c0 = *(const half8*)(rowp);
            half8 c1 = *(const half8*)(rowp + 8);
            half8 c2 = *(const half8*)(rowp + 16);
            half8 c3 = *(const half8*)(rowp + 24);
            float s = 0.f, dd = 0.f;
            #pragma unroll
            for (int j = 0; j < 8; ++j) {
                s  = fmaf((float)c0[j], As_r[j],      s);
                dd = fmaf((float)c0[j], Ad_r[j],      dd);
                s  = fmaf((float)c1[j], As_r[8 + j],  s);
                dd = fmaf((float)c1[j], Ad_r[8 + j],  dd);
                s  = fmaf((float)c2[j], As_r[16 + j], s);
                dd = fmaf((float)c2[j], Ad_r[16 + j], dd);
                s  = fmaf((float)c3[j], As_r[24 + j], s);
                dd = fmaf((float)c3[j], Ad_r[24 + j], dd);
            }
            as_o[rg] = s;
            ad_o[rg] = dd;
            _Float16* hr = h + (size_t)rg * OUT_DIM;
            *(half8*)(hr)      = c0;
            *(half8*)(hr + 8)  = c1;
            *(half8*)(hr + 16) = c2;
            *(half8*)(hr + 24) = c3;
        }
    }
}

// ---------------- Aggregation (segment softmax + weighted sum, gather-only) ----

// Layer 1: one wave per dst node. 8 lanes per edge x 8 edge groups; fp16 h rows,
// fp32 accumulate (v_fma_mix). Writes helu as fp16 (gemm2 A-operand).
__global__ __launch_bounds__(256) void agg1_k(const int* __restrict__ deg,
        const int* __restrict__ csr, const _Float16* __restrict__ h1,
        const float* __restrict__ as1, const float* __restrict__ ad1,
        const float* __restrict__ b1, _Float16* __restrict__ helu) {
    int d = (blockIdx.x * 256 + threadIdx.x) >> 6;
    int lane = threadIdx.x & 63;
    int eg = lane >> 3;          // edge group 0..7
    int cl = lane & 7;           // 8-half channel group
    int head = cl >> 2;          // cl 0-3 -> head 0 (ch 0-31), 4-7 -> head 1
    int cnt = deg[d];
    const int* row = csr + d * SLOTS;
    float advl = ad1[d * 2 + head];
    float acc[8] = {0.f, 0.f, 0.f, 0.f, 0.f, 0.f, 0.f, 0.f};
    float wsum = 0.f;
    for (int base = 0; base < cnt; base += 16) {
        int e0 = base + eg, e1 = base + 8 + eg;
        bool v0 = e0 < cnt, v1 = e1 < cnt;
        int s0 = row[v0 ? e0 : 0];
        int s1 = row[v1 ? e1 : 0];
        float a0 = as1[s0 * 2 + head];
        float a1 = as1[s1 * 2 + head];
        half8 g0 = *(const half8*)(h1 + (size_t)s0 * C1 + 8 * cl);
        half8 g1 = *(const half8*)(h1 + (size_t)s1 * C1 + 8 * cl);
        float w0 = lrelu_exp(a0 + advl) * (v0 ? 1.f : 0.f);
        float w1 = lrelu_exp(a1 + advl) * (v1 ? 1.f : 0.f);
        #pragma unroll
        for (int i = 0; i < 8; ++i) {
            acc[i] = fmaf((float)g0[i], w0, acc[i]);
            acc[i] = fmaf((float)g1[i], w1, acc[i]);
        }
        wsum += w0 + w1;
    }
    if (eg == 0) {   // self loop (src = dst)
        float w = lrelu_exp(as1[d * 2 + head] + advl);
        half8 g = *(const half8*)(h1 + (size_t)d * C1 + 8 * cl);
        #pragma unroll
        for (int i = 0; i < 8; ++i) acc[i] = fmaf((float)g[i], w, acc[i]);
        wsum += w;
    }
    #pragma unroll
    for (int m = 8; m <= 32; m <<= 1) {   // butterfly over eg axis
        #pragma unroll
        for (int i = 0; i < 8; ++i) acc[i] += __shfl_xor(acc[i], m);
        wsum += __shfl_xor(wsum, m);
    }
    if (eg == 0) {
        float inv = 1.f / (wsum + 1e-16f);
        const float4* bv = (const float4*)(b1 + 8 * cl);
        float o[8];
        #pragma unroll
        for (int i = 0; i < 4; ++i) {
            o[i]     = acc[i]     * inv + (&bv[0].x)[i];
            o[4 + i] = acc[4 + i] * inv + (&bv[1].x)[i];
        }
        half8 hv;
        #pragma unroll
        for (int i = 0; i < 8; ++i) {
            float e = o[i] > 0.f ? o[i] : __expf(o[i]) - 1.f;   // ELU
            hv[i] = (_Float16)e;
        }
        *(half8*)(helu + (size_t)d * C1 + 8 * cl) = hv;
    }
}

// Layer 2: 4 lanes per edge x 16 edge groups; cl = lane&3 spans the 64B row.
// Butterfly over xor 4/8/16/32. Mean over 1 head = identity; +b2. Output fp32.
__global__ __launch_bounds__(256) void agg2_k(const int* __restrict__ deg,
        const int* __restrict__ csr, const _Float16* __restrict__ h2,
        const float* __restrict__ as2, const float* __restrict__ ad2,
        const float* __restrict__ b2, float* __restrict__ out) {
    int d = (blockIdx.x * 256 + threadIdx.x) >> 6;
    int lane = threadIdx.x & 63;
    int eg = lane >> 2;          // edge group 0..15
    int cl = lane & 3;           // 8-half channel group
    int cnt = deg[d];
    const int* row = csr + d * SLOTS;
    float advl = ad2[d];
    float acc[8] = {0.f, 0.f, 0.f, 0.f, 0.f, 0.f, 0.f, 0.f};
    float wsum = 0.f;
    for (int base = 0; base < cnt; base += 32) {
        int e0 = base + eg, e1 = base + 16 + eg;
        bool v0 = e0 < cnt, v1 = e1 < cnt;
        int s0 = row[v0 ? e0 : 0];
        int s1 = row[v1 ? e1 : 0];
        float a0 = as2[s0];
        float a1 = as2[s1];
        half8 g0 = *(const half8*)(h2 + (size_t)s0 * OUT_DIM + 8 * cl);
        half8 g1 = *(const half8*)(h2 + (size_t)s1 * OUT_DIM + 8 * cl);
        float w0 = lrelu_exp(a0 + advl) * (v0 ? 1.f : 0.f);
        float w1 = lrelu_exp(a1 + advl) * (v1 ? 1.f : 0.f);
        #pragma unroll
        for (int i = 0; i < 8; ++i) {
            acc[i] = fmaf((float)g0[i], w0, acc[i]);
            acc[i] = fmaf((float)g1[i], w1, acc[i]);
        }
        wsum += w0 + w1;
    }
    if (eg == 0) {   // self loop
        float w = lrelu_exp(as2[d] + advl);
        half8 g = *(const half8*)(h2 + (size_t)d * OUT_DIM + 8 * cl);
        #pragma unroll
        for (int i = 0; i < 8; ++i) acc[i] = fmaf((float)g[i], w, acc[i]);
        wsum += w;
    }
    #pragma unroll
    for (int m = 4; m <= 32; m <<= 1) {    // butterfly over eg axis
        #pragma unroll
        for (int i = 0; i < 8; ++i) acc[i] += __shfl_xor(acc[i], m);
        wsum += __shfl_xor(wsum, m);
    }
    if (eg == 0) {
        float inv = 1.f / (wsum + 1e-16f);
        const float4* bv = (const float4*)(b2 + 8 * cl);
        float4 o0, o1;
        o0.x = acc[0] * inv + bv[0].x; o0.y = acc[1] * inv + bv[0].y;
        o0.z = acc[2] * inv + bv[0].z; o0.w = acc[3] * inv + bv[0].w;
        o1.x = acc[4] * inv + bv[1].x; o1.y = acc[5] * inv + bv[1].y;
        o1.z = acc[6] * inv + bv[1].z; o1.w = acc[7] * inv + bv[1].w;
        float4* ow = (float4*)(out + (size_t)d * OUT_DIM + 8 * cl);
        ow[0] = o0;
        ow[1] = o1;
    }
}

// ---------------- launch ----------------

extern "C" void kernel_launch(void* const* d_in, const int* in_sizes, int n_in,
                              void* d_out, int out_size, void* d_ws, size_t ws_size,
                              hipStream_t stream) {
    const float* x   = (const float*)d_in[0];
    const int*   ei  = (const int*)d_in[1];
    const float* W1  = (const float*)d_in[2];
    const float* a1s = (const float*)d_in[3];
    const float* a1d = (const float*)d_in[4];
    const float* b1  = (const float*)d_in[5];
    const float* W2  = (const float*)d_in[6];
    const float* a2s = (const float*)d_in[7];
    const float* a2d = (const float*)d_in[8];
    const float* b2  = (const float*)d_in[9];
    float* out = (float*)d_out;

    char* ws = (char*)d_ws;
    size_t off = 0;
    auto alloc = [&](size_t bytes) -> void* {
        void* p = ws + off;
        off = (off + bytes + 255) & ~(size_t)255;
        return p;
    };
    int* gcur      = (int*)alloc((size_t)NBUCK * GC_STRIDE * 4);        // 25 KB
    int* buf       = (int*)alloc((size_t)NBUCK * CAP * 4);              // 8 MB
    int* csr       = (int*)alloc((size_t)NBUCK * BNODES * SLOTS * 4);   // 19.2 MB
    int* deg       = (int*)alloc((size_t)NBUCK * BNODES * 4);           // 0.4 MB
    _Float16* w1t  = (_Float16*)alloc((size_t)IN_DIM * C1 * 2);         // 16 KB
    _Float16* w2t  = (_Float16*)alloc((size_t)C1 * OUT_DIM * 2);        // 4 KB
    _Float16* h1   = (_Float16*)alloc((size_t)N_NODES * C1 * 2);        // 12.8 MB
    float* as1     = (float*)alloc((size_t)N_NODES * 2 * 4);
    float* ad1     = (float*)alloc((size_t)N_NODES * 2 * 4);
    _Float16* helu = (_Float16*)alloc((size_t)N_NODES * C1 * 2);        // 12.8 MB
    _Float16* h2   = (_Float16*)alloc((size_t)N_NODES * OUT_DIM * 2);   // 6.4 MB
    float* as2     = (float*)alloc((size_t)N_NODES * 4);
    float* ad2     = (float*)alloc((size_t)N_NODES * 4);

    const int ZN4 = NBUCK * GC_STRIDE / 4;
    zero_k<<<(ZN4 + 255) / 256, 256, 0, stream>>>((int4*)gcur, ZN4);
    binp1_k<<<(N_EDGES + 16383) / 16384, 1024, 0, stream>>>(ei, gcur, buf);
    binp2_k<<<NBUCK, 256, 0, stream>>>(gcur, buf, csr, deg);
    prep_k<<<(IN_DIM * C1 + 255) / 256, 256, 0, stream>>>(W1, W2, w1t, w2t);

    gemm1_k<<<G1_BLOCKS, 256, 0, stream>>>(x, w1t, a1s, a1d, h1, as1, ad1);
    agg1_k<<<N_NODES / 4, 256, 0, stream>>>(deg, csr, h1, as1, ad1, b1, helu);
    gemm2_k<<<G1_BLOCKS, 256, 0, stream>>>(helu, w2t, a2s, a2d, h2, as2, ad2);
    agg2_k<<<N_NODES / 4, 256, 0, stream>>>(deg, csr, h2, as2, ad2, b2, out);
}